// Round 1
// baseline (2914.902 us; speedup 1.0000x reference)
//
#include <hip/hip_runtime.h>
#include <hip/hip_bf16.h>
#include <math.h>

#define SEQ 70
#define HID 230
#define G3  690
#define EMBD 50
#define DIN 60
#define NTOT 2048
#define NREL 100
#define NBAG 64
#define BAGSZ 32
#define PDIM 5
#define MB 8   // sentences per GRU block

// ---------------- prep kernels ----------------

__global__ void k_zero(float* p, long n) {
    long i = (long)blockIdx.x * 256 + threadIdx.x;
    if (i < n) p[i] = 0.f;
}

__global__ void k_embed(const int* __restrict__ sent, const int* __restrict__ p1,
                        const int* __restrict__ p2,  const float* __restrict__ wemb,
                        const float* __restrict__ t1, const float* __restrict__ t2,
                        float* __restrict__ emb) {
    long idx = (long)blockIdx.x * 256 + threadIdx.x;
    long total = (long)NTOT * SEQ * DIN;
    if (idx >= total) return;
    int nt = (int)(idx / DIN);
    int j  = (int)(idx % DIN);
    float v;
    if (j < EMBD)            v = wemb[(long)sent[nt] * EMBD + j];
    else if (j < EMBD + PDIM) v = t1[p1[nt] * PDIM + (j - EMBD)];
    else                      v = t2[p2[nt] * PDIM + (j - EMBD - PDIM)];
    emb[idx] = v;
}

// in[g*K+k] -> out[k*G+g]
__global__ void k_transpose(const float* __restrict__ in, float* __restrict__ out,
                            int G, int K) {
    int idx = blockIdx.x * 256 + threadIdx.x;
    if (idx >= G * K) return;
    int g = idx / K, k = idx % K;
    out[k * G + g] = in[idx];
}

// ---------------- GRU (both directions in one launch) ----------------
// grid = (NTOT/MB)*2 blocks, 256 threads. blockIdx.x&1 = direction.
// tup must be zeroed beforehand; both directions atomicAdd into it.
__global__ __launch_bounds__(256) void k_gru(
    const float* __restrict__ emb,
    const float* __restrict__ wihT_f, const float* __restrict__ whhT_f,
    const float* __restrict__ bih_f,  const float* __restrict__ bhh_f,
    const float* __restrict__ wihT_b, const float* __restrict__ whhT_b,
    const float* __restrict__ bih_b,  const float* __restrict__ bhh_b,
    float* __restrict__ tup) {

    const bool rev = blockIdx.x & 1;
    const int  n0  = (blockIdx.x >> 1) * MB;
    const float* wihT = rev ? wihT_b : wihT_f;
    const float* whhT = rev ? whhT_b : whhT_f;
    const float* bih  = rev ? bih_b  : bih_f;
    const float* bhh  = rev ? bhh_b  : bhh_f;
    const int tid = threadIdx.x;

    __shared__ float h_s[HID * MB];   // [k][n]
    __shared__ float e_s[DIN * MB];   // [k][n]
    __shared__ float P_s[G3 * MB];    // gate pre-activations (combined for r,z; i_n for n-gate)
    __shared__ float Q_s[HID * MB];   // h_n part of n-gate

    for (int i = tid; i < HID * MB; i += 256) h_s[i] = 0.f;

    const int g0 = tid;            // < 256  (always r or z gate)
    const int g1 = tid + 256;      // < 512
    const int g2 = tid + 512;      // valid if < 690 (always n-gate)
    const bool v2 = (g2 < G3);

    const float bi0 = bih[g0], bh0 = bhh[g0];
    const float bi1 = bih[g1], bh1 = bhh[g1];
    const float bi2 = v2 ? bih[g2] : 0.f, bh2 = v2 ? bhh[g2] : 0.f;

    for (int t = 0; t < SEQ; ++t) {
        const int tt = rev ? (SEQ - 1 - t) : t;

        // stage emb tile [60][MB]
        for (int i = tid; i < DIN * MB; i += 256) {
            int n = i / DIN, k = i - n * DIN;
            e_s[k * MB + n] = emb[((long)(n0 + n) * SEQ + tt) * DIN + k];
        }
        __syncthreads();   // S1: also separates prev combine (P/Q/h readers) from writes below

        float a0[MB], a1[MB], a2[MB], h0[MB], h1[MB], h2[MB];
#pragma unroll
        for (int n = 0; n < MB; ++n) {
            a0[n] = bi0; a1[n] = bi1; a2[n] = bi2;
            h0[n] = bh0; h1[n] = bh1; h2[n] = bh2;
        }
        // input projection, K = 60
        for (int k = 0; k < DIN; ++k) {
            float w0 = wihT[k * G3 + g0];
            float w1 = wihT[k * G3 + g1];
            float w2 = v2 ? wihT[k * G3 + g2] : 0.f;
            const float4* ep = (const float4*)&e_s[k * MB];
            float4 ea = ep[0], eb = ep[1];
            float ev[8] = {ea.x, ea.y, ea.z, ea.w, eb.x, eb.y, eb.z, eb.w};
#pragma unroll
            for (int n = 0; n < MB; ++n) {
                a0[n] = fmaf(w0, ev[n], a0[n]);
                a1[n] = fmaf(w1, ev[n], a1[n]);
                a2[n] = fmaf(w2, ev[n], a2[n]);
            }
        }
        // hidden projection, K = 230
        for (int k = 0; k < HID; ++k) {
            float w0 = whhT[k * G3 + g0];
            float w1 = whhT[k * G3 + g1];
            float w2 = v2 ? whhT[k * G3 + g2] : 0.f;
            const float4* hp = (const float4*)&h_s[k * MB];
            float4 ha = hp[0], hb = hp[1];
            float hv[8] = {ha.x, ha.y, ha.z, ha.w, hb.x, hb.y, hb.z, hb.w};
#pragma unroll
            for (int n = 0; n < MB; ++n) {
                h0[n] = fmaf(w0, hv[n], h0[n]);
                h1[n] = fmaf(w1, hv[n], h1[n]);
                h2[n] = fmaf(w2, hv[n], h2[n]);
            }
        }
        // publish gate pre-activations
#pragma unroll
        for (int n = 0; n < MB; ++n) P_s[g0 * MB + n] = a0[n] + h0[n];
        if (g1 < 2 * HID) {
#pragma unroll
            for (int n = 0; n < MB; ++n) P_s[g1 * MB + n] = a1[n] + h1[n];
        } else {
#pragma unroll
            for (int n = 0; n < MB; ++n) {
                P_s[g1 * MB + n] = a1[n];
                Q_s[(g1 - 2 * HID) * MB + n] = h1[n];
            }
        }
        if (v2) {
#pragma unroll
            for (int n = 0; n < MB; ++n) {
                P_s[g2 * MB + n] = a2[n];
                Q_s[(g2 - 2 * HID) * MB + n] = h2[n];
            }
        }
        __syncthreads();   // S2

        // combine gates -> new h, write to tup
        for (int e = tid; e < HID * MB; e += 256) {
            int n = e / HID, hh = e - n * HID;
            int idx = hh * MB + n;
            float r = 1.f / (1.f + expf(-P_s[idx]));
            float z = 1.f / (1.f + expf(-P_s[(HID + hh) * MB + n]));
            float nn = tanhf(P_s[(2 * HID + hh) * MB + n] + r * Q_s[idx]);
            float hold = h_s[idx];
            float hnew = (1.f - z) * nn + z * hold;
            h_s[idx] = hnew;
            atomicAdd(&tup[((long)(n0 + n) * SEQ + tt) * HID + hh], hnew);
        }
    }
}

// ---------------- word-level attention ----------------
__global__ __launch_bounds__(256) void k_wordattn(
    const float* __restrict__ tup, const float* __restrict__ attw,
    const float* __restrict__ sen_a, const float* __restrict__ sen_r,
    float* __restrict__ repre, float* __restrict__ sbuf) {
    const int n = blockIdx.x, tid = threadIdx.x;
    __shared__ float tl[SEQ * HID];   // 64400 B
    __shared__ float sc[SEQ];
    __shared__ float red[4];
    for (int i = tid; i < SEQ * HID; i += 256) tl[i] = tup[(long)n * SEQ * HID + i];
    __syncthreads();
    if (tid < SEQ) {
        float s = 0.f;
        for (int h = 0; h < HID; ++h) s += tanhf(tl[tid * HID + h]) * attw[h];
        sc[tid] = s;
    }
    __syncthreads();
    if (tid == 0) {
        float m = sc[0];
        for (int t = 1; t < SEQ; ++t) m = fmaxf(m, sc[t]);
        float ssum = 0.f;
        for (int t = 0; t < SEQ; ++t) { float e = expf(sc[t] - m); sc[t] = e; ssum += e; }
        float inv = 1.f / ssum;
        for (int t = 0; t < SEQ; ++t) sc[t] *= inv;
    }
    __syncthreads();
    float part = 0.f;
    if (tid < HID) {
        float r = 0.f;
        for (int t = 0; t < SEQ; ++t) r = fmaf(sc[t], tl[t * HID + tid], r);
        float rep = tanhf(r);
        repre[(long)n * HID + tid] = rep;
        part = rep * sen_a[tid] * sen_r[tid];
    }
    for (int off = 32; off; off >>= 1) part += __shfl_down(part, off, 64);
    if ((tid & 63) == 0) red[tid >> 6] = part;
    __syncthreads();
    if (tid == 0) sbuf[n] = red[0] + red[1] + red[2] + red[3];
}

// ---------------- bag attention + logits + loss + prob + acc ----------------
__global__ __launch_bounds__(256) void k_bag(
    const float* __restrict__ repre, const float* __restrict__ sbuf,
    const float* __restrict__ rel, const float* __restrict__ sen_d,
    const float* __restrict__ y, float* __restrict__ out, float* __restrict__ bagloss) {
    const int b = blockIdx.x, tid = threadIdx.x;
    __shared__ float al[BAGSZ];
    __shared__ float ss[HID];
    __shared__ float lg[NREL];
    if (tid == 0) {
        float m = -1e30f;
        for (int i = 0; i < BAGSZ; ++i) m = fmaxf(m, sbuf[b * BAGSZ + i]);
        float s = 0.f;
        for (int i = 0; i < BAGSZ; ++i) { float e = expf(sbuf[b * BAGSZ + i] - m); al[i] = e; s += e; }
        float inv = 1.f / s;
        for (int i = 0; i < BAGSZ; ++i) al[i] *= inv;
    }
    __syncthreads();
    if (tid < HID) {
        float acc = 0.f;
        for (int i = 0; i < BAGSZ; ++i)
            acc = fmaf(al[i], repre[(long)(b * BAGSZ + i) * HID + tid], acc);
        ss[tid] = acc;
    }
    __syncthreads();
    if (tid < NREL) {
        float acc = sen_d[tid];
        for (int h = 0; h < HID; ++h) acc = fmaf(ss[h], rel[tid * HID + h], acc);
        lg[tid] = acc;
    }
    __syncthreads();
    if (tid == 0) {
        float m = -1e30f; int am = 0;
        for (int r = 0; r < NREL; ++r) if (lg[r] > m) { m = lg[r]; am = r; }
        float s = 0.f;
        for (int r = 0; r < NREL; ++r) s += expf(lg[r] - m);
        float inv = 1.f / s;
        float ym = -1e30f; int ay = 0;
        for (int r = 0; r < NREL; ++r) { float yy = y[b * NREL + r]; if (yy > ym) { ym = yy; ay = r; } }
        out[1 + b] = (am == ay) ? 1.f : 0.f;
        float loss = 0.f;
        for (int r = 0; r < NREL; ++r) {
            float l = lg[r], yy = y[b * NREL + r];
            loss += fmaxf(l, 0.f) - l * yy + log1pf(expf(-fabsf(l)));
            out[1 + NBAG + b * NREL + r] = expf(l - m) * inv;
        }
        bagloss[b] = loss / NREL;
    }
}

__global__ void k_final(const float* __restrict__ bagloss, float* __restrict__ out) {
    if (blockIdx.x == 0 && threadIdx.x == 0) {
        float s = 0.f;
        for (int i = 0; i < NBAG; ++i) s += bagloss[i];
        out[0] = s;
    }
}

// ---------------- host launcher ----------------
extern "C" void kernel_launch(void* const* d_in, const int* in_sizes, int n_in,
                              void* d_out, int out_size, void* d_ws, size_t ws_size,
                              hipStream_t stream) {
    const int*   sent   = (const int*)d_in[0];
    const int*   pos1   = (const int*)d_in[1];
    const int*   pos2   = (const int*)d_in[2];
    // d_in[3] = total_shape (bag layout is fixed: 64 bags x 32)
    const float* ybatch = (const float*)d_in[4];
    const float* wemb   = (const float*)d_in[5];
    const float* p1tab  = (const float*)d_in[6];
    const float* p2tab  = (const float*)d_in[7];
    const float* Wih_f  = (const float*)d_in[8];
    const float* Whh_f  = (const float*)d_in[9];
    const float* bih_f  = (const float*)d_in[10];
    const float* bhh_f  = (const float*)d_in[11];
    const float* Wih_b  = (const float*)d_in[12];
    const float* Whh_b  = (const float*)d_in[13];
    const float* bih_b  = (const float*)d_in[14];
    const float* bhh_b  = (const float*)d_in[15];
    const float* attw   = (const float*)d_in[16];
    const float* sen_a  = (const float*)d_in[17];
    const float* sen_r  = (const float*)d_in[18];
    const float* rel    = (const float*)d_in[19];
    const float* sen_d  = (const float*)d_in[20];
    float* out = (float*)d_out;

    float* ws = (float*)d_ws;
    size_t off = 0;
    float* emb    = ws + off; off += (size_t)NTOT * SEQ * DIN;   // 8,601,600
    float* wihT_f = ws + off; off += (size_t)DIN * G3;
    float* wihT_b = ws + off; off += (size_t)DIN * G3;
    float* whhT_f = ws + off; off += (size_t)HID * G3;
    float* whhT_b = ws + off; off += (size_t)HID * G3;
    float* tup    = ws + off; off += (size_t)NTOT * SEQ * HID;   // 32,998,400
    float* repre  = ws + off; off += (size_t)NTOT * HID;
    float* sbuf   = ws + off; off += (size_t)NTOT;
    float* bagloss= ws + off; off += (size_t)NBAG;

    const long tupN = (long)NTOT * SEQ * HID;
    k_zero<<<(int)((tupN + 255) / 256), 256, 0, stream>>>(tup, tupN);

    const long embN = (long)NTOT * SEQ * DIN;
    k_embed<<<(int)((embN + 255) / 256), 256, 0, stream>>>(sent, pos1, pos2, wemb, p1tab, p2tab, emb);

    k_transpose<<<(G3 * DIN + 255) / 256, 256, 0, stream>>>(Wih_f, wihT_f, G3, DIN);
    k_transpose<<<(G3 * DIN + 255) / 256, 256, 0, stream>>>(Wih_b, wihT_b, G3, DIN);
    k_transpose<<<(G3 * HID + 255) / 256, 256, 0, stream>>>(Whh_f, whhT_f, G3, HID);
    k_transpose<<<(G3 * HID + 255) / 256, 256, 0, stream>>>(Whh_b, whhT_b, G3, HID);

    k_gru<<<(NTOT / MB) * 2, 256, 0, stream>>>(emb,
        wihT_f, whhT_f, bih_f, bhh_f,
        wihT_b, whhT_b, bih_b, bhh_b, tup);

    k_wordattn<<<NTOT, 256, 0, stream>>>(tup, attw, sen_a, sen_r, repre, sbuf);

    k_bag<<<NBAG, 256, 0, stream>>>(repre, sbuf, rel, sen_d, ybatch, out, bagloss);

    k_final<<<1, 64, 0, stream>>>(bagloss, out);
}